// Round 6
// baseline (127.230 us; speedup 1.0000x reference)
//
#include <hip/hip_runtime.h>

// ACELoss3D round 6: R5 + XCD-contiguous block swizzle.
// Each pred z-row is consumed 9x by different blocks (center, x+-1, y+-1,
// 4 corners). Default dispatch round-robins blocks across the 8 XCDs, so
// y-halo/corner partners (logical b+-1, b+-1+-16) land on DIFFERENT XCDs and
// their reads miss per-XCD L2 -> LLC (~300MB extra LLC traffic). Swizzle
// logical = (d&7)*1536 + (d>>3): each XCD owns a contiguous 1536-block slab,
// all halo reuse becomes same-XCD L2 hits (active window ~1-2MB << 4MB L2).
// Everything else identical to R5 (shuffle z-halo, two-kernel reduction).

static constexpr int   NTOT   = 6 * 128 * 128 * 128;   // 12,582,912
static constexpr int   NG     = NTOT / 4;              // 3,145,728 groups
static constexpr int   NBLK   = 12288;                 // NBLK*256 == NG exactly
static constexpr float ALPHA_ = 0.001f;
static constexpr float MIU_   = 1.0f;
static constexpr float EPS_   = 1e-8f;

__device__ __forceinline__ void wave_reduce3(float& a, float& b, float& c) {
#pragma unroll
  for (int off = 32; off > 0; off >>= 1) {
    a += __shfl_down(a, off);
    b += __shfl_down(b, off);
    c += __shfl_down(c, off);
  }
}

// One output element. di/dj = un-halved first diffs; sx/sy = uxp+uxm, uyp+uym;
// dik/djk/dij = un-halved mixed double-diffs. 2*cik*cjk*cij = 0.25*dik*djk*dij.
__device__ __forceinline__ void elem(
    float uzm, float u0, float uzp,
    float di, float sx, float dj, float sy,
    float dik, float djk, float dij,
    float t, float& s1, float& s2, float& s3) {
  const float dk  = uzp - uzm;
  const float ci2 = 0.25f * di * di;
  const float cj2 = 0.25f * dj * dj;
  const float ck2 = 0.25f * dk * dk;
  const float u2  = u0 + u0;
  const float cii = sx - u2;
  const float cjj = sy - u2;
  const float ckk = (uzp + uzm) - u2;
  const float ss  = ci2 + cj2 + ck2;
  const float ss1 = 1.f + ss;
  const float L = (cii + cjj) + ckk;
  const float M = fmaf(ci2, cii, fmaf(cj2, cjj, ck2 * ckk));
  float curv = fmaf(ss1, L, -M);
  curv = fmaf(-0.25f * dij, dik * djk, curv);
  const float len = __builtin_amdgcn_sqrtf(EPS_ + ss);
  s3 = fmaf(curv * curv, len * __builtin_amdgcn_rcpf(ss1), s3);
  const float tm1 = t - 1.f;
  s1 = fmaf(u0, tm1 * tm1, s1);
  s2 = fmaf(1.f - u0, t * t, s2);
}

__global__ __launch_bounds__(256) void ace_main(
    const float* __restrict__ pred, const float* __restrict__ truth,
    float* __restrict__ partials) {
  const int tid = threadIdx.x;
  // XCD-contiguous swizzle: HW assigns dispatched block d to XCD d%8 (round
  // robin). Give XCD k the contiguous logical slab [k*1536, (k+1)*1536).
  const int d  = blockIdx.x;
  const int lb = (d & 7) * (NBLK / 8) + (d >> 3);
  const int g  = lb * 256 + tid;                   // 0..NG-1, exact cover

  const int z0 = (g & 31) << 2;                    // 0,4,...,124
  const int y  = (g >> 5) & 127;
  const int x  = (g >> 12) & 127;
  const size_t base = ((size_t)(g >> 19)) << 21;
  const float* __restrict__ bp = pred + base;

  const int rC  = y << 7;
  const int rYp = ((y < 127) ? y + 1 : 127) << 7;
  const int rYm = ((y > 0)   ? y - 1 : 0)   << 7;
  const int pC  = x << 14;
  const int pXp = ((x < 127) ? x + 1 : 127) << 14;
  const int pXm = ((x > 0)   ? x - 1 : 0)   << 14;

  // 10 float4 loads — the ONLY vector-memory reads in the kernel.
  const float4 vC  = *(const float4*)(bp + pC  + rC  + z0);
  const float4 vXP = *(const float4*)(bp + pXp + rC  + z0);
  const float4 vXM = *(const float4*)(bp + pXm + rC  + z0);
  const float4 vYP = *(const float4*)(bp + pC  + rYp + z0);
  const float4 vYM = *(const float4*)(bp + pC  + rYm + z0);
  const float4 vPP = *(const float4*)(bp + pXp + rYp + z0);
  const float4 vMP = *(const float4*)(bp + pXm + rYp + z0);
  const float4 vPM = *(const float4*)(bp + pXp + rYm + z0);
  const float4 vMM = *(const float4*)(bp + pXm + rYm + z0);
  const float4 t4  = *(const float4*)(truth + base + pC + rC + z0);

  // Early combines.
  const float dxa = vXP.x - vXM.x, dxb = vXP.y - vXM.y;
  const float dxc = vXP.z - vXM.z, dxd = vXP.w - vXM.w;
  const float sxa = vXP.x + vXM.x, sxb = vXP.y + vXM.y;
  const float sxc = vXP.z + vXM.z, sxd = vXP.w + vXM.w;
  const float dya = vYP.x - vYM.x, dyb = vYP.y - vYM.y;
  const float dyc = vYP.z - vYM.z, dyd = vYP.w - vYM.w;
  const float sya = vYP.x + vYM.x, syb = vYP.y + vYM.y;
  const float syc = vYP.z + vYM.z, syd = vYP.w + vYM.w;
  const float ja = (vPP.x - vMP.x) - (vPM.x - vMM.x);
  const float jb = (vPP.y - vMP.y) - (vPM.y - vMM.y);
  const float jc = (vPP.z - vMP.z) - (vPM.z - vMM.z);
  const float jd = (vPP.w - vMP.w) - (vPM.w - vMM.w);

  // z-boundary values from adjacent lanes (lane i-1 holds z0-4..z0-1).
  // Clamp lanes: z0==0 (lanes 0,32): z-1 -> z=0 (own .x); z0==124 (lanes
  // 31,63): z+4 -> z=127 (own .w). Shuffles never cross the wave.
  const bool zlo = (z0 == 0), zhi = (z0 == 124);
  float clo  = __shfl_up  (vC.w, 1);  clo  = zlo ? vC.x : clo;
  float chi  = __shfl_down(vC.x, 1);  chi  = zhi ? vC.w : chi;
  float dxm1 = __shfl_up  (dxd, 1);   dxm1 = zlo ? dxa : dxm1;
  float dxp4 = __shfl_down(dxa, 1);   dxp4 = zhi ? dxd : dxp4;
  float dym1 = __shfl_up  (dyd, 1);   dym1 = zlo ? dya : dym1;
  float dyp4 = __shfl_down(dya, 1);   dyp4 = zhi ? dyd : dyp4;

  float s1 = 0.f, s2 = 0.f, s3 = 0.f;
  elem(clo,  vC.x, vC.y, dxa, sxa, dya, sya, dxb - dxm1, dyb - dym1, ja, t4.x, s1, s2, s3);
  elem(vC.x, vC.y, vC.z, dxb, sxb, dyb, syb, dxc - dxa,  dyc - dya,  jb, t4.y, s1, s2, s3);
  elem(vC.y, vC.z, vC.w, dxc, sxc, dyc, syc, dxd - dxb,  dyd - dyb,  jc, t4.z, s1, s2, s3);
  elem(vC.z, vC.w, chi,  dxd, sxd, dyd, syd, dxp4 - dxc, dyp4 - dyc, jd, t4.w, s1, s2, s3);

  wave_reduce3(s1, s2, s3);
  __shared__ float l1[4], l2[4], l3[4];
  const int lane = tid & 63, wv = tid >> 6;
  if (lane == 0) { l1[wv] = s1; l2[wv] = s2; l3[wv] = s3; }
  __syncthreads();
  if (tid == 0) {
    partials[blockIdx.x]            = l1[0] + l1[1] + l1[2] + l1[3];
    partials[NBLK + blockIdx.x]     = l2[0] + l2[1] + l2[2] + l2[3];
    partials[2 * NBLK + blockIdx.x] = l3[0] + l3[1] + l3[2] + l3[3];
  }
}

__global__ __launch_bounds__(1024) void ace_final(
    const float* __restrict__ partials, float* __restrict__ out) {
  const int tid = threadIdx.x;
  float s1 = 0.f, s2 = 0.f, s3 = 0.f;
  const float4* p1 = (const float4*)(partials);
  const float4* p2 = (const float4*)(partials + NBLK);
  const float4* p3 = (const float4*)(partials + 2 * NBLK);
#pragma unroll
  for (int i = 0; i < NBLK / 4 / 1024; ++i) {
    const float4 a = p1[i * 1024 + tid];
    const float4 b = p2[i * 1024 + tid];
    const float4 c = p3[i * 1024 + tid];
    s1 += (a.x + a.y) + (a.z + a.w);
    s2 += (b.x + b.y) + (b.z + b.w);
    s3 += (c.x + c.y) + (c.z + c.w);
  }
  wave_reduce3(s1, s2, s3);
  __shared__ float l1[16], l2[16], l3[16];
  const int lane = tid & 63, wv = tid >> 6;
  if (lane == 0) { l1[wv] = s1; l2[wv] = s2; l3[wv] = s3; }
  __syncthreads();
  if (tid == 0) {
    float S1 = 0.f, S2 = 0.f, S3 = 0.f;
#pragma unroll
    for (int w = 0; w < 16; ++w) { S1 += l1[w]; S2 += l2[w]; S3 += l3[w]; }
    out[0] = MIU_ * fabsf(S1) + fabsf(S2) + S3 + ALPHA_ * (float)NTOT;
  }
}

extern "C" void kernel_launch(void* const* d_in, const int* in_sizes, int n_in,
                              void* d_out, int out_size, void* d_ws, size_t ws_size,
                              hipStream_t stream) {
  const float* pred  = (const float*)d_in[0];   // y_pred
  const float* truth = (const float*)d_in[1];   // y_true
  float* out      = (float*)d_out;
  float* partials = (float*)d_ws;               // 3*NBLK floats = 147 KB

  ace_main<<<NBLK, 256, 0, stream>>>(pred, truth, partials);
  ace_final<<<1, 1024, 0, stream>>>(partials, out);
}